// Round 10
// baseline (493.287 us; speedup 1.0000x reference)
//
#include <hip/hip_runtime.h>

// Round 10: algebraic restructure — tp term computed as 4 plain K=128 GEMMs
// (A = raw de-interleaved f, B = Wt[:,v,:]) combined in the fp32 accumulator:
//   tp[n,w] = sum_v attr[n,v] * (sum_u f[n,u] Wt[u,v,w])
// This deletes the per-element f*attr A-build (r9's dominant VALU cost:
// VALUBusy 38% vs MfmaUtil 12%).  MFMA count unchanged; numerics improve.

#define MUL 128
#define DIM 512
#define KTOT 640
#define NSTEPS 20
#define NODES 16
#define INV_LIN 0.08838834764831845f   // 1/sqrt(128)
#define INV_TP  0.04419417382415922f   // 1/sqrt(512)

typedef float f32x4 __attribute__((ext_vector_type(4)));
typedef __bf16 bf16x8 __attribute__((ext_vector_type(8)));

__device__ inline unsigned short f2bf(float x) {
    unsigned u = __float_as_uint(x);
    u += 0x7fffu + ((u >> 16) & 1u);
    return (unsigned short)(u >> 16);
}

// ---------------------------------------------------------------------------
// Prep: combined weights, fragment-major (r9-validated packing formula).
// NEW k-axis semantics (sections): kst = k>>5 (0..19), sec = k>>7, u = k&127.
//   sec==0   : B[w][k] = Wl[u][w] * INV_LIN          (lin)
//   sec==1+v : B[w][k] = Wt[u][v][w] * INV_TP        (tp slice v)
// Packing: ct=w>>5, ct2=(w>>4)&1, lr=w&15; ks=k>>5, g=(k>>3)&3, i=k&7
//   P[(((ct*20+ks)*2+ct2)*64 + g*16+lr)*8 + i]
// ---------------------------------------------------------------------------
__global__ __launch_bounds__(256) void prep_weights(
        const float* __restrict__ Wl0, const float* __restrict__ Wl1,
        const float* __restrict__ Wt0, const float* __restrict__ Wt1,
        unsigned short* __restrict__ P0, unsigned short* __restrict__ P1) {
    int idx = blockIdx.x * 256 + threadIdx.x;
    if (idx >= 2 * MUL * KTOT) return;
    int mat = idx / (MUL * KTOT);
    int r   = idx % (MUL * KTOT);
    int w = r / KTOT, k = r % KTOT;
    const float* Wl = mat ? Wl1 : Wl0;
    const float* Wt = mat ? Wt1 : Wt0;
    int sec = k >> 7, u = k & 127;
    float val;
    if (sec == 0) {
        val = Wl[u * MUL + w] * INV_LIN;
    } else {
        val = Wt[u * 512 + (sec - 1) * 128 + w] * INV_TP;
    }
    int ct = w >> 5, ct2 = (w >> 4) & 1, lr = w & 15;
    int ks = k >> 5, g = (k >> 3) & 3, i = k & 7;
    (mat ? P1 : P0)[((((ct * NSTEPS + ks) * 2 + ct2) * 64 + g * 16 + lr) << 3) + i] = f2bf(val);
}

// ---------------------------------------------------------------------------
// Fused kernel: 16 nodes/block, 256 threads, 4 waves; wave ct owns cols
// ct*32..ct*32+31 (2 sub-tiles) x 4 classes.  A in LDS de-interleaved
// (validated).  B streamed from L2.  Zero barriers in K-loop.
// tp: per v, 4-kstep GEMM into tmp, then fp32 combine with attr.
// ---------------------------------------------------------------------------
#define POOL_BYTES 34816   // Mde+Fde 2*4*16*136*2 = 34816 ; Ost 32768 reuses it
__global__ __launch_bounds__(256, 4) void k_fused(
        const float* __restrict__ m_i, const float* __restrict__ nf,
        const float* __restrict__ attrs,
        const bf16x8* __restrict__ P0, const bf16x8* __restrict__ P1,
        float* __restrict__ out, int N) {
    __shared__ __align__(16) char pool[POOL_BYTES];
    __bf16 (*Mde)[NODES][136] = (__bf16(*)[NODES][136])(pool);          // [4][16][136]
    __bf16 (*Fde)[NODES][136] = (__bf16(*)[NODES][136])(pool + 17408);

    int tid = threadIdx.x;
    int ct = tid >> 6, l = tid & 63;      // ct = 32-col group
    int lr = l & 15, g = l >> 4;

    long nodeBase = (long)blockIdx.x * NODES;

    // ---- stage A de-interleaved (validated): class 0 = cols 0..127;
    //      class 1+c = col 128 + u*3 + c  ->  Mde/Fde[class][node][u] ----
    for (int c = tid; c < NODES * 128; c += 256) {
        int nl = c >> 7, q = c & 127;
        long node = nodeBase + nl; if (node >= N) node = N - 1;
        f32x4 x = *(const f32x4*)&m_i[node * DIM + q * 4];
        f32x4 y = *(const f32x4*)&nf [node * DIM + q * 4];
        #pragma unroll
        for (int j = 0; j < 4; ++j) {
            int col = q * 4 + j;
            int cls, u;
            if (col < 128) { cls = 0; u = col; }
            else { int cc = col - 128; cls = 1 + cc % 3; u = cc / 3; }
            Mde[cls][nl][u] = (__bf16)x[j];
            Fde[cls][nl][u] = (__bf16)y[j];
        }
    }

    // attr rows matching the D/acc row mapping (node = nodeBase + g*4 + r)
    f32x4 at_row[4];
    #pragma unroll
    for (int r = 0; r < 4; ++r) {
        long nd = nodeBase + g * 4 + r; if (nd >= N) nd = N - 1;
        at_row[r] = *(const f32x4*)&attrs[nd * 4];
    }

    f32x4 acc[4][2] = {};
    __syncthreads();

    // ---- lin: sec 0, ksteps 0..3 ----
    #pragma unroll
    for (int ks = 0; ks < 4; ++ks) {
        bf16x8 b0[2], b1[2];
        #pragma unroll
        for (int c2 = 0; c2 < 2; ++c2) {
            b0[c2] = P0[((ct * NSTEPS + ks) * 2 + c2) * 64 + l];
            b1[c2] = P1[((ct * NSTEPS + ks) * 2 + c2) * 64 + l];
        }
        #pragma unroll
        for (int cls = 0; cls < 4; ++cls) {
            bf16x8 af = *(const bf16x8*)&Mde[cls][lr][ks * 32 + g * 8];
            #pragma unroll
            for (int c2 = 0; c2 < 2; ++c2)
                acc[cls][c2] = __builtin_amdgcn_mfma_f32_16x16x32_bf16(
                    af, cls ? b1[c2] : b0[c2], acc[cls][c2], 0, 0, 0);
        }
    }

    // ---- tp: per v, 4-kstep GEMM into tmp, fp32 combine with attr ----
    #pragma unroll
    for (int v = 0; v < 4; ++v) {
        f32x4 tmp[4][2] = {};
        #pragma unroll
        for (int ks = 0; ks < 4; ++ks) {
            int kst = (1 + v) * 4 + ks;
            bf16x8 b0[2], b1[2];
            #pragma unroll
            for (int c2 = 0; c2 < 2; ++c2) {
                b0[c2] = P0[((ct * NSTEPS + kst) * 2 + c2) * 64 + l];
                b1[c2] = P1[((ct * NSTEPS + kst) * 2 + c2) * 64 + l];
            }
            #pragma unroll
            for (int cls = 0; cls < 4; ++cls) {
                bf16x8 af = *(const bf16x8*)&Fde[cls][lr][ks * 32 + g * 8];
                #pragma unroll
                for (int c2 = 0; c2 < 2; ++c2)
                    tmp[cls][c2] = __builtin_amdgcn_mfma_f32_16x16x32_bf16(
                        af, cls ? b1[c2] : b0[c2], tmp[cls][c2], 0, 0, 0);
            }
        }
        #pragma unroll
        for (int cls = 0; cls < 4; ++cls)
            #pragma unroll
            for (int c2 = 0; c2 < 2; ++c2)
                #pragma unroll
                for (int r = 0; r < 4; ++r)
                    acc[cls][c2][r] += at_row[r][v] * tmp[cls][c2][r];
    }

    // ---- epilogue (validated): acc -> Ost -> coalesced dump ----
    __syncthreads();                       // all K-loop LDS reads done
    float (*Ost)[DIM] = (float(*)[DIM])pool;     // [16][512]
    #pragma unroll
    for (int c2 = 0; c2 < 2; ++c2) {
        int wv_ = ct * 32 + c2 * 16 + lr;
        #pragma unroll
        for (int r = 0; r < 4; ++r) {
            int nl = g * 4 + r;
            Ost[nl][wv_]               = acc[0][c2][r];   // s  : col = w
            Ost[nl][128 + wv_ * 3 + 0] = acc[1][c2][r];   // xyz: col = 128+w*3+m
            Ost[nl][128 + wv_ * 3 + 1] = acc[2][c2][r];
            Ost[nl][128 + wv_ * 3 + 2] = acc[3][c2][r];
        }
    }
    __syncthreads();
    for (int c = tid; c < NODES * 128; c += 256) {
        int nl = c >> 7, q = c & 127;
        long node = nodeBase + nl;
        if (node < N)
            *(f32x4*)&out[node * DIM + q * 4] = *(const f32x4*)&Ost[nl][q * 4];
    }
}

extern "C" void kernel_launch(void* const* d_in, const int* in_sizes, int n_in,
                              void* d_out, int out_size, void* d_ws, size_t ws_size,
                              hipStream_t stream) {
    const float* m_i  = (const float*)d_in[0];
    const float* nf   = (const float*)d_in[1];
    const float* attr = (const float*)d_in[2];
    const float* Wl0  = (const float*)d_in[3];
    const float* Wl1  = (const float*)d_in[4];
    const float* Wt0  = (const float*)d_in[5];
    const float* Wt1  = (const float*)d_in[6];
    float* out = (float*)d_out;
    int N = in_sizes[0] / DIM;

    unsigned short* P0 = (unsigned short*)d_ws;     // 160KB packed fragments
    unsigned short* P1 = P0 + MUL * KTOT;           // 160KB

    int prep_total = 2 * MUL * KTOT;
    hipLaunchKernelGGL(prep_weights, dim3((prep_total + 255) / 256), dim3(256), 0, stream,
                       Wl0, Wl1, Wt0, Wt1, P0, P1);
    hipLaunchKernelGGL(k_fused, dim3((N + NODES - 1) / NODES), dim3(256), 0, stream,
                       m_i, nf, attr, (const bf16x8*)P0, (const bf16x8*)P1, out, N);
}

// Round 11
// 213.264 us; speedup vs baseline: 2.3130x; 2.3130x over previous
//
#include <hip/hip_runtime.h>

// Round 11: r10's validated algebraic structure (tp = 4 plain K=128 GEMMs
// + fp32 attr-combine), with the REGISTER BUDGET fixed.
// r10 failed on scheduling, not math: __launch_bounds__(256,4) capped VGPRs
// at 128 < ~160 live -> ~1GB scratch traffic (WRITE 979MB, FETCH 689MB).
// Fix: bound (256,2) -> 256-VGPR budget, no spill; occupancy ~3 waves/SIMD.

#define MUL 128
#define DIM 512
#define KTOT 640
#define NSTEPS 20
#define NODES 16
#define INV_LIN 0.08838834764831845f   // 1/sqrt(128)
#define INV_TP  0.04419417382415922f   // 1/sqrt(512)

typedef float f32x4 __attribute__((ext_vector_type(4)));
typedef __bf16 bf16x8 __attribute__((ext_vector_type(8)));

__device__ inline unsigned short f2bf(float x) {
    unsigned u = __float_as_uint(x);
    u += 0x7fffu + ((u >> 16) & 1u);
    return (unsigned short)(u >> 16);
}

// ---------------------------------------------------------------------------
// Prep: combined weights, fragment-major (validated r9/r10).
// k-axis sections: sec = k>>7, u = k&127.
//   sec==0   : B[w][k] = Wl[u][w] * INV_LIN          (lin)
//   sec==1+v : B[w][k] = Wt[u][v][w] * INV_TP        (tp slice v)
// Packing: ct=w>>5, ct2=(w>>4)&1, lr=w&15; ks=k>>5, g=(k>>3)&3, i=k&7
//   P[(((ct*20+ks)*2+ct2)*64 + g*16+lr)*8 + i]
// ---------------------------------------------------------------------------
__global__ __launch_bounds__(256) void prep_weights(
        const float* __restrict__ Wl0, const float* __restrict__ Wl1,
        const float* __restrict__ Wt0, const float* __restrict__ Wt1,
        unsigned short* __restrict__ P0, unsigned short* __restrict__ P1) {
    int idx = blockIdx.x * 256 + threadIdx.x;
    if (idx >= 2 * MUL * KTOT) return;
    int mat = idx / (MUL * KTOT);
    int r   = idx % (MUL * KTOT);
    int w = r / KTOT, k = r % KTOT;
    const float* Wl = mat ? Wl1 : Wl0;
    const float* Wt = mat ? Wt1 : Wt0;
    int sec = k >> 7, u = k & 127;
    float val;
    if (sec == 0) {
        val = Wl[u * MUL + w] * INV_LIN;
    } else {
        val = Wt[u * 512 + (sec - 1) * 128 + w] * INV_TP;
    }
    int ct = w >> 5, ct2 = (w >> 4) & 1, lr = w & 15;
    int ks = k >> 5, g = (k >> 3) & 3, i = k & 7;
    (mat ? P1 : P0)[((((ct * NSTEPS + ks) * 2 + ct2) * 64 + g * 16 + lr) << 3) + i] = f2bf(val);
}

// ---------------------------------------------------------------------------
// Fused kernel: 16 nodes/block, 256 threads, 4 waves; wave ct owns cols
// ct*32..ct*32+31 (2 sub-tiles) x 4 classes.  A in LDS de-interleaved
// (validated).  B streamed from L2.  Zero barriers in K-loop.
// tp: per v, 4-kstep GEMM into tmp, then fp32 combine with attr.
// ---------------------------------------------------------------------------
#define POOL_BYTES 34816   // Mde+Fde 2*4*16*136*2 = 34816 ; Ost 32768 reuses it
__global__ __launch_bounds__(256, 2) void k_fused(
        const float* __restrict__ m_i, const float* __restrict__ nf,
        const float* __restrict__ attrs,
        const bf16x8* __restrict__ P0, const bf16x8* __restrict__ P1,
        float* __restrict__ out, int N) {
    __shared__ __align__(16) char pool[POOL_BYTES];
    __bf16 (*Mde)[NODES][136] = (__bf16(*)[NODES][136])(pool);          // [4][16][136]
    __bf16 (*Fde)[NODES][136] = (__bf16(*)[NODES][136])(pool + 17408);

    int tid = threadIdx.x;
    int ct = tid >> 6, l = tid & 63;      // ct = 32-col group
    int lr = l & 15, g = l >> 4;

    long nodeBase = (long)blockIdx.x * NODES;

    // ---- stage A de-interleaved (validated): class 0 = cols 0..127;
    //      class 1+c = col 128 + u*3 + c  ->  Mde/Fde[class][node][u] ----
    for (int c = tid; c < NODES * 128; c += 256) {
        int nl = c >> 7, q = c & 127;
        long node = nodeBase + nl; if (node >= N) node = N - 1;
        f32x4 x = *(const f32x4*)&m_i[node * DIM + q * 4];
        f32x4 y = *(const f32x4*)&nf [node * DIM + q * 4];
        #pragma unroll
        for (int j = 0; j < 4; ++j) {
            int col = q * 4 + j;
            int cls, u;
            if (col < 128) { cls = 0; u = col; }
            else { int cc = col - 128; cls = 1 + cc % 3; u = cc / 3; }
            Mde[cls][nl][u] = (__bf16)x[j];
            Fde[cls][nl][u] = (__bf16)y[j];
        }
    }

    // attr rows matching the D/acc row mapping (node = nodeBase + g*4 + r)
    f32x4 at_row[4];
    #pragma unroll
    for (int r = 0; r < 4; ++r) {
        long nd = nodeBase + g * 4 + r; if (nd >= N) nd = N - 1;
        at_row[r] = *(const f32x4*)&attrs[nd * 4];
    }

    f32x4 acc[4][2] = {};
    __syncthreads();

    // ---- lin: sec 0, ksteps 0..3 ----
    #pragma unroll
    for (int ks = 0; ks < 4; ++ks) {
        bf16x8 b0[2], b1[2];
        #pragma unroll
        for (int c2 = 0; c2 < 2; ++c2) {
            b0[c2] = P0[((ct * NSTEPS + ks) * 2 + c2) * 64 + l];
            b1[c2] = P1[((ct * NSTEPS + ks) * 2 + c2) * 64 + l];
        }
        #pragma unroll
        for (int cls = 0; cls < 4; ++cls) {
            bf16x8 af = *(const bf16x8*)&Mde[cls][lr][ks * 32 + g * 8];
            #pragma unroll
            for (int c2 = 0; c2 < 2; ++c2)
                acc[cls][c2] = __builtin_amdgcn_mfma_f32_16x16x32_bf16(
                    af, cls ? b1[c2] : b0[c2], acc[cls][c2], 0, 0, 0);
        }
    }

    // ---- tp: per v, 4-kstep GEMM into tmp, fp32 combine with attr ----
    #pragma unroll
    for (int v = 0; v < 4; ++v) {
        f32x4 tmp[4][2] = {};
        #pragma unroll
        for (int ks = 0; ks < 4; ++ks) {
            int kst = (1 + v) * 4 + ks;
            bf16x8 b0[2], b1[2];
            #pragma unroll
            for (int c2 = 0; c2 < 2; ++c2) {
                b0[c2] = P0[((ct * NSTEPS + kst) * 2 + c2) * 64 + l];
                b1[c2] = P1[((ct * NSTEPS + kst) * 2 + c2) * 64 + l];
            }
            #pragma unroll
            for (int cls = 0; cls < 4; ++cls) {
                bf16x8 af = *(const bf16x8*)&Fde[cls][lr][ks * 32 + g * 8];
                #pragma unroll
                for (int c2 = 0; c2 < 2; ++c2)
                    tmp[cls][c2] = __builtin_amdgcn_mfma_f32_16x16x32_bf16(
                        af, cls ? b1[c2] : b0[c2], tmp[cls][c2], 0, 0, 0);
            }
        }
        #pragma unroll
        for (int cls = 0; cls < 4; ++cls)
            #pragma unroll
            for (int c2 = 0; c2 < 2; ++c2)
                #pragma unroll
                for (int r = 0; r < 4; ++r)
                    acc[cls][c2][r] += at_row[r][v] * tmp[cls][c2][r];
    }

    // ---- epilogue (validated): acc -> Ost -> coalesced dump ----
    __syncthreads();                       // all K-loop LDS reads done
    float (*Ost)[DIM] = (float(*)[DIM])pool;     // [16][512]
    #pragma unroll
    for (int c2 = 0; c2 < 2; ++c2) {
        int wv_ = ct * 32 + c2 * 16 + lr;
        #pragma unroll
        for (int r = 0; r < 4; ++r) {
            int nl = g * 4 + r;
            Ost[nl][wv_]               = acc[0][c2][r];   // s  : col = w
            Ost[nl][128 + wv_ * 3 + 0] = acc[1][c2][r];   // xyz: col = 128+w*3+m
            Ost[nl][128 + wv_ * 3 + 1] = acc[2][c2][r];
            Ost[nl][128 + wv_ * 3 + 2] = acc[3][c2][r];
        }
    }
    __syncthreads();
    for (int c = tid; c < NODES * 128; c += 256) {
        int nl = c >> 7, q = c & 127;
        long node = nodeBase + nl;
        if (node < N)
            *(f32x4*)&out[node * DIM + q * 4] = *(const f32x4*)&Ost[nl][q * 4];
    }
}

extern "C" void kernel_launch(void* const* d_in, const int* in_sizes, int n_in,
                              void* d_out, int out_size, void* d_ws, size_t ws_size,
                              hipStream_t stream) {
    const float* m_i  = (const float*)d_in[0];
    const float* nf   = (const float*)d_in[1];
    const float* attr = (const float*)d_in[2];
    const float* Wl0  = (const float*)d_in[3];
    const float* Wl1  = (const float*)d_in[4];
    const float* Wt0  = (const float*)d_in[5];
    const float* Wt1  = (const float*)d_in[6];
    float* out = (float*)d_out;
    int N = in_sizes[0] / DIM;

    unsigned short* P0 = (unsigned short*)d_ws;     // 160KB packed fragments
    unsigned short* P1 = P0 + MUL * KTOT;           // 160KB

    int prep_total = 2 * MUL * KTOT;
    hipLaunchKernelGGL(prep_weights, dim3((prep_total + 255) / 256), dim3(256), 0, stream,
                       Wl0, Wl1, Wt0, Wt1, P0, P1);
    hipLaunchKernelGGL(k_fused, dim3((N + NODES - 1) / NODES), dim3(256), 0, stream,
                       m_i, nf, attr, (const bf16x8*)P0, (const bf16x8*)P1, out, N);
}